// Round 4
// baseline (382.629 us; speedup 1.0000x reference)
//
#include <hip/hip_runtime.h>

#define B_    2
#define S_    2048
#define H_    16
#define HS_   128
#define HID_  2048
#define N_QKV 6144
#define SCALE_Q 0.08838834764831845f  // 1/sqrt(128)

typedef unsigned short ushort_t;
typedef __attribute__((ext_vector_type(8))) __bf16 bf16x8;
typedef __attribute__((ext_vector_type(4))) float f32x4;
typedef __attribute__((ext_vector_type(16))) float f32x16;

__device__ __forceinline__ float bf2f(ushort_t u) {
  union { unsigned int i; float f; } x; x.i = ((unsigned int)u) << 16; return x.f;
}
__device__ __forceinline__ ushort_t f2bf(float f) {
  union { float f; unsigned int i; } x; x.f = f;
  unsigned int u = x.i;
  u += 0x7fffu + ((u >> 16) & 1u);   // RNE
  return (ushort_t)(u >> 16);
}
// async global->LDS, 16B per lane; LDS dest = wave-uniform base + lane*16
__device__ __forceinline__ void gload16(const ushort_t* g, ushort_t* l) {
  __builtin_amdgcn_global_load_lds(
      (__attribute__((address_space(1))) void*)g,
      (__attribute__((address_space(3))) void*)l, 16, 0, 0);
}

// ---------------- fused prep: X->bf16 conv + both weight transposes ----------------
// blocks [0,4096): conv (8 floats/thread)
// blocks [4096,7168): Wqkv (2048x6144) -> WqkvT (6144x2048) bf16, 64x64 tiles
// blocks [7168,8192): Wd (2048x2048) -> WdT bf16

__global__ __launch_bounds__(256) void prep(
    const float* __restrict__ hs, const float* __restrict__ Wq,
    const float* __restrict__ Wd, ushort_t* __restrict__ Xb,
    ushort_t* __restrict__ WqT, ushort_t* __restrict__ WdT) {
  __shared__ float t[64][65];
  int bx = blockIdx.x, tid = threadIdx.x;
  if (bx < 4096) {
    size_t i = ((size_t)bx * 256 + tid) * 8;
    float4 a = *(const float4*)(hs + i);
    float4 b = *(const float4*)(hs + i + 4);
    ushort4 o0; o0.x = f2bf(a.x); o0.y = f2bf(a.y); o0.z = f2bf(a.z); o0.w = f2bf(a.w);
    ushort4 o1; o1.x = f2bf(b.x); o1.y = f2bf(b.y); o1.z = f2bf(b.z); o1.w = f2bf(b.w);
    *(ushort4*)(Xb + i) = o0;
    *(ushort4*)(Xb + i + 4) = o1;
    return;
  }
  const float* in; ushort_t* out; int C, r0, c0;
  const int R = HID_;
  if (bx < 7168) {
    int tt = bx - 4096; C = N_QKV;
    c0 = (tt % 96) * 64; r0 = (tt / 96) * 64;
    in = Wq; out = WqT;
  } else {
    int tt = bx - 7168; C = HID_;
    c0 = (tt & 31) * 64; r0 = (tt >> 5) * 64;
    in = Wd; out = WdT;
  }
  int row = tid >> 4, col4 = (tid & 15) * 4;
#pragma unroll
  for (int i = 0; i < 4; ++i) {
    float4 v = *(const float4*)(in + (size_t)(r0 + row + i * 16) * C + c0 + col4);
    t[row + i * 16][col4 + 0] = v.x;
    t[row + i * 16][col4 + 1] = v.y;
    t[row + i * 16][col4 + 2] = v.z;
    t[row + i * 16][col4 + 3] = v.w;
  }
  __syncthreads();
#pragma unroll
  for (int i = 0; i < 4; ++i) {
    int cl = (tid >> 4) + i * 16;
    int r4 = (tid & 15) * 4;
    ushort4 o;
    o.x = f2bf(t[r4 + 0][cl]);
    o.y = f2bf(t[r4 + 1][cl]);
    o.z = f2bf(t[r4 + 2][cl]);
    o.w = f2bf(t[r4 + 3][cl]);
    *(ushort4*)(out + (size_t)(c0 + cl) * R + r0 + r4) = o;
  }
}

// ======= BK=64 XOR-swizzled GEMM core (staging + K-loop), shared by both GEMMs ======
// LDS tile: 128 rows x 64 cols bf16 = 16 KB, stored as 8 granules(16B)/row with
// phys granule p = r*8 + (g ^ (r&7)).  Staging lane l of chunk ch fetches
// row = ch*8 + (l>>3), logical granule (l&7)^(l>>3)  -> LDS slot ch*64+l.
// Fragment reads hit p%8 = g^(l16&7): 2-way bank aliasing (free).

#define GEMM_KLOOP(As, Bs, Ab, Bb, K)                                            \
  for (int kt = 0; kt < (K); kt += 64) {                                         \
    __syncthreads();                                                             \
    _Pragma("unroll")                                                            \
    for (int j = 0; j < 4; ++j) {                                                \
      int ch = wave * 4 + j;                                                     \
      gload16((Ab) + (size_t)(ch * 8 + lr) * (K) + kt + lg * 8, &(As)[ch * 512]);\
      gload16((Bb) + (size_t)(ch * 8 + lr) * (K) + kt + lg * 8, &(Bs)[ch * 512]);\
    }                                                                            \
    __syncthreads();                                                             \
    _Pragma("unroll")                                                            \
    for (int ks2 = 0; ks2 < 2; ++ks2) {                                          \
      bf16x8 af[4], bfr[4];                                                      \
      _Pragma("unroll")                                                          \
      for (int i = 0; i < 4; ++i) {                                              \
        int r = wm * 64 + i * 16 + l16;                                          \
        af[i] = *(const bf16x8*)&(As)[(r * 8 + ((ks2 * 4 + quad) ^ (r & 7))) * 8];\
      }                                                                          \
      _Pragma("unroll")                                                          \
      for (int j = 0; j < 4; ++j) {                                              \
        int r = wn * 64 + j * 16 + l16;                                          \
        bfr[j] = *(const bf16x8*)&(Bs)[(r * 8 + ((ks2 * 4 + quad) ^ (r & 7))) * 8];\
      }                                                                          \
      _Pragma("unroll")                                                          \
      for (int i = 0; i < 4; ++i)                                                \
        _Pragma("unroll")                                                        \
        for (int j = 0; j < 4; ++j)                                              \
          acc[i][j] = __builtin_amdgcn_mfma_f32_16x16x32_bf16(af[i], bfr[j],     \
                                                              acc[i][j], 0, 0, 0);\
    }                                                                            \
  }

// ---------------- fused QKV GEMM: X(4096x2048) @ WqkvT^T + rotary + scatter ----------
// Each 128-col tile == one (head, part) slice: part 0 -> Qb(b,h,s,d) w/ rotary+scale,
// part 1 -> Kb(b,h,s,d) w/ rotary, part 2 -> Vt(b,h,d,s) transposed (8B stores).

__global__ __launch_bounds__(256, 2) void gemm_qkv(
    const ushort_t* __restrict__ A, const ushort_t* __restrict__ Bt,
    const float* __restrict__ bias, const int* __restrict__ pids,
    ushort_t* __restrict__ Qb, ushort_t* __restrict__ Kb, ushort_t* __restrict__ Vt) {
  const int K = HID_;
  __shared__ alignas(16) ushort_t As[128 * 64];
  __shared__ alignas(16) ushort_t Bs[128 * 64];
  int tid = threadIdx.x;
  int wave = tid >> 6, lane = tid & 63;
  int quad = lane >> 4, l16 = lane & 15;
  int wm = wave >> 1, wn = wave & 1;
  int r0 = blockIdx.y * 128, c0 = blockIdx.x * 128;

  const ushort_t* Ab = A + (size_t)r0 * K;
  const ushort_t* Bb = Bt + (size_t)c0 * K;
  int lr = lane >> 3;               // row within 8-row chunk
  int lg = (lane & 7) ^ lr;         // swizzled logical granule

  f32x4 acc[4][4];
#pragma unroll
  for (int i = 0; i < 4; ++i)
#pragma unroll
    for (int j = 0; j < 4; ++j) acc[i][j] = (f32x4){0.f, 0.f, 0.f, 0.f};

  GEMM_KLOOP(As, Bs, Ab, Bb, K)

  int hh = blockIdx.x / 3, part = blockIdx.x % 3;
  float bv[4];
#pragma unroll
  for (int j = 0; j < 4; ++j) bv[j] = bias[c0 + wn * 64 + j * 16 + l16];

  if (part == 2) {
    // V: row chunk = 4 consecutive s at same d -> transposed 8B stores
#pragma unroll
    for (int i = 0; i < 4; ++i) {
      int row = r0 + wm * 64 + i * 16 + quad * 4;
      int b = row >> 11, s = row & (S_ - 1);
#pragma unroll
      for (int j = 0; j < 4; ++j) {
        int d = wn * 64 + j * 16 + l16;
        ushort4 pk;
        pk.x = f2bf(acc[i][j][0] + bv[j]);
        pk.y = f2bf(acc[i][j][1] + bv[j]);
        pk.z = f2bf(acc[i][j][2] + bv[j]);
        pk.w = f2bf(acc[i][j][3] + bv[j]);
        *(ushort4*)&Vt[((size_t)(b * H_ + hh) * HS_ + d) * S_ + s] = pk;
      }
    }
  } else {
    ushort_t* Dst = (part == 0) ? Qb : Kb;
    float scale = (part == 0) ? SCALE_Q : 1.0f;
    float invf = __expf((float)l16 * (-9.210340371976184f / 16.0f)); // 10000^(-l16/16)
#pragma unroll
    for (int i = 0; i < 4; ++i) {
#pragma unroll
      for (int r = 0; r < 4; ++r) {
        int row = r0 + wm * 64 + i * 16 + quad * 4 + r;
        int b = row >> 11, s = row & (S_ - 1);
        size_t obase = ((size_t)(b * H_ + hh) * S_ + s) * HS_ + wn * 64;
        float vals[4];
#pragma unroll
        for (int j = 0; j < 4; ++j) vals[j] = acc[i][j][r] + bv[j];
        if (wn == 0) {
          // rotary: d0 = l16 (j=0), d1 = 16+l16 (j=1); pass for j>=2
          int pos = pids[row];
          float sn, cs;
          sincosf((float)pos * invf, &sn, &cs);
          float v0 = vals[0], v1 = vals[1];
          vals[0] = v0 * cs - v1 * sn;
          vals[1] = v1 * cs + v0 * sn;
        }
#pragma unroll
        for (int j = 0; j < 4; ++j)
          Dst[obase + j * 16 + l16] = f2bf(vals[j] * scale);
      }
    }
  }
}

// ---------------- BK=64 swizzled bf16 GEMM: C = A(MxK) @ Bt(NxK)^T + bias ----------

template <int BF16OUT>
__global__ __launch_bounds__(256, 2) void gemm_bt(
    const ushort_t* __restrict__ A, const ushort_t* __restrict__ Bt,
    const float* __restrict__ bias, void* __restrict__ Cv,
    int M, int N, int K) {
  __shared__ alignas(16) ushort_t As[128 * 64];
  __shared__ alignas(16) ushort_t Bs[128 * 64];
  int tid = threadIdx.x;
  int wave = tid >> 6, lane = tid & 63;
  int quad = lane >> 4, l16 = lane & 15;
  int wm = wave >> 1, wn = wave & 1;
  int r0 = blockIdx.y * 128, c0 = blockIdx.x * 128;

  const ushort_t* Ab = A + (size_t)r0 * K;
  const ushort_t* Bb = Bt + (size_t)c0 * K;
  int lr = lane >> 3;
  int lg = (lane & 7) ^ lr;

  f32x4 acc[4][4];
#pragma unroll
  for (int i = 0; i < 4; ++i)
#pragma unroll
    for (int j = 0; j < 4; ++j) acc[i][j] = (f32x4){0.f, 0.f, 0.f, 0.f};

  GEMM_KLOOP(As, Bs, Ab, Bb, K)

  float* Cf = (float*)Cv;
  ushort_t* Chh = (ushort_t*)Cv;
#pragma unroll
  for (int i = 0; i < 4; ++i) {
    int row = r0 + wm * 64 + i * 16 + quad * 4;
#pragma unroll
    for (int j = 0; j < 4; ++j) {
      int col = c0 + wn * 64 + j * 16 + l16;
      float bvv = bias[col];
#pragma unroll
      for (int r = 0; r < 4; ++r) {
        float v = acc[i][j][r] + bvv;
        size_t idx = (size_t)(row + r) * N + col;
        if (BF16OUT) Chh[idx] = f2bf(v);
        else         Cf[idx] = v;
      }
    }
  }
}

// ---------------- flash attention: 32x32 swapped-QK, in-register P (T12) ----------------
// Q,K: (B,H,S,HS) bf16 (Q pre-scaled); Vt: (B,H,HS,S) bf16; out: (B,S,HID) bf16
// QK: S^T = mfma_32x32x16(K, Q): lane&31 = q-col; keys land in-lane via C-row map
//   key(blk,reg,hi) = blk*32 + (reg&3) + 8*(reg>>2) + 4*hi   (hi = lane>>5)
// Softmax: in-lane over 32 keys + 1 shfl_xor(32) partner combine (rows split across
//   lane pairs L, L+32). T13 defer-max (THR=8) skips O-rescale.
// P -> PV A-frags IN REGISTER (no LDS P): 16 v_cvt_pk_bf16_f32 + 8 v_permlane32_swap
//   per tile: pa[ks=2blk+k1].word{j, j+2} = swap(w[blk][2k1][j], w[blk][2k1+1][j]).
//   (A-frag 32x32x16: row=lane&31, k=(lane>>5)*8+e — extends the harness-verified
//    16x16x32 mapping row=lane&15, k=(lane>>4)*8+e.)
// PV: O = mfma_32x32x16(P, V): vf B-frags read from Vs (d-major) = V^T directly.
// K/V staging, swizzles, double-buffer, grid, q-tile balance: unchanged (verified).

__global__ __launch_bounds__(256, 2) void flash_attn(
    const ushort_t* __restrict__ Q, const ushort_t* __restrict__ Kg,
    const ushort_t* __restrict__ Vt, const float* __restrict__ mask,
    ushort_t* __restrict__ Out) {
  __shared__ alignas(16) ushort_t Ks[2][64 * 128];
  __shared__ alignas(16) ushort_t Vs[2][128 * 64];

  int x = blockIdx.x, y = blockIdx.y;
  int qi = (x & 1) ? (x >> 1) : (15 - (x >> 1));   // consecutive-x pairs sum to 15
  if (y & 16) qi = 15 - qi;                        // stride-256 pairs also sum to 15
  int q0 = qi * 128;
  int bh = y;
  int b = bh >> 4, h = bh & 15;
  const ushort_t* Qh = Q + (size_t)bh * S_ * HS_;
  const ushort_t* Kh = Kg + (size_t)bh * S_ * HS_;
  const ushort_t* Vh = Vt + (size_t)bh * HS_ * S_;
  const float* mk = mask + (size_t)b * S_;

  int tid = threadIdx.x;
  int wave = tid >> 6, lane = tid & 63;
  int l31 = lane & 31, hi = lane >> 5;
  int qg = q0 + wave * 32 + l31;   // this lane's softmax q-row

  // Q fragments (B-operand): col = lane&31 = q, k(d) = ks*16 + hi*8 + e
  bf16x8 qf[8];
#pragma unroll
  for (int ks = 0; ks < 8; ++ks)
    qf[ks] = *(const bf16x8*)(Qh + (size_t)qg * HS_ + ks * 16 + hi * 8);

  f32x16 o[4];
#pragma unroll
  for (int d = 0; d < 4; ++d)
#pragma unroll
    for (int r = 0; r < 16; ++r) o[d][r] = 0.f;
  float mrow = -1e30f, lrow = 0.f;

  int ntiles = q0 / 64 + 2;

#pragma unroll
  for (int j = 0; j < 4; ++j) {
    int ch = wave * 4 + j;
    {
      int p = ch * 64 + lane;
      int r = p >> 4, g = (p & 15) ^ (r & 15);
      gload16(Kh + (size_t)r * HS_ + g * 8, &Ks[0][ch * 512]);
    }
    {
      int p = ch * 64 + lane;
      int r = p >> 3, g = (p & 7) ^ (r & 7);
      gload16(Vh + (size_t)r * S_ + g * 8, &Vs[0][ch * 512]);
    }
  }

  for (int it = 0; it < ntiles; ++it) {
    int bsel = it & 1;
    int n0 = it * 64;
    __syncthreads();

    if (it + 1 < ntiles) {
      int n1 = n0 + 64;
#pragma unroll
      for (int j = 0; j < 4; ++j) {
        int ch = wave * 4 + j;
        {
          int p = ch * 64 + lane;
          int r = p >> 4, g = (p & 15) ^ (r & 15);
          gload16(Kh + (size_t)(n1 + r) * HS_ + g * 8, &Ks[bsel ^ 1][ch * 512]);
        }
        {
          int p = ch * 64 + lane;
          int r = p >> 3, g = (p & 7) ^ (r & 7);
          gload16(Vh + (size_t)r * S_ + n1 + g * 8, &Vs[bsel ^ 1][ch * 512]);
        }
      }
    }

    bool edge = (it >= ntiles - 2);

    // ---- QK^T: 2 key-blocks x 8 k-steps of mfma_32x32x16(K, Q)
    f32x16 sa[2];
#pragma unroll
    for (int blk = 0; blk < 2; ++blk) {
      f32x16 a;
#pragma unroll
      for (int r = 0; r < 16; ++r) a[r] = 0.f;
      int row = blk * 32 + l31;  // key row in Ks
      __builtin_amdgcn_s_setprio(1);
#pragma unroll
      for (int ks = 0; ks < 8; ++ks) {
        bf16x8 kf = *(const bf16x8*)&Ks[bsel][(row * 16 + ((ks * 2 + hi) ^ (row & 15))) * 8];
        a = __builtin_amdgcn_mfma_f32_32x32x16_bf16(kf, qf[ks], a, 0, 0, 0);
      }
      __builtin_amdgcn_s_setprio(0);
      sa[blk] = a;
    }

    // ---- mask add + causal + row max (in-lane 32 keys, partner combine)
    float mx = -1e30f;
#pragma unroll
    for (int blk = 0; blk < 2; ++blk)
#pragma unroll
      for (int g = 0; g < 4; ++g) {
        int kbase = n0 + blk * 32 + g * 8 + hi * 4;
        f32x4 mv = *(const f32x4*)&mk[kbase];
#pragma unroll
        for (int j = 0; j < 4; ++j) {
          float v = sa[blk][g * 4 + j] + mv[j];
          if (edge && (kbase + j > qg)) v = -1e30f;
          sa[blk][g * 4 + j] = v;
          mx = fmaxf(mx, v);
        }
      }
    mx = fmaxf(mx, __shfl_xor(mx, 32, 64));

    // T13 defer-max
    bool defer = (mrow > -1e29f) && __all(mx <= mrow + 8.0f);
    float mnew = mrow, alpha = 1.0f;
    if (!defer) {
      mnew = fmaxf(mrow, mx);
      alpha = __expf(mrow - mnew);
      mrow = mnew;
    }
    float rs = 0.f;
#pragma unroll
    for (int blk = 0; blk < 2; ++blk)
#pragma unroll
      for (int r = 0; r < 16; ++r) {
        float pv = __expf(sa[blk][r] - mnew);
        sa[blk][r] = pv;
        rs += pv;
      }
    rs += __shfl_xor(rs, 32, 64);
    if (defer) {
      lrow += rs;
    } else {
      lrow = lrow * alpha + rs;
      // O rows live in regs (row map), alpha lives in lane q: broadcast per reg
#pragma unroll
      for (int r = 0; r < 16; ++r) {
        float ar = __shfl(alpha, (r & 3) + 8 * (r >> 2) + 4 * hi, 64);
#pragma unroll
        for (int d = 0; d < 4; ++d) o[d][r] *= ar;
      }
    }

    // ---- P -> bf16 A-frags in-register: cvt_pk + permlane32_swap (T12)
    unsigned int w[2][4][2];
#pragma unroll
    for (int blk = 0; blk < 2; ++blk)
#pragma unroll
      for (int g = 0; g < 4; ++g) {
        asm("v_cvt_pk_bf16_f32 %0, %1, %2"
            : "=v"(w[blk][g][0]) : "v"(sa[blk][g * 4 + 0]), "v"(sa[blk][g * 4 + 1]));
        asm("v_cvt_pk_bf16_f32 %0, %1, %2"
            : "=v"(w[blk][g][1]) : "v"(sa[blk][g * 4 + 2]), "v"(sa[blk][g * 4 + 3]));
      }
    union PW { unsigned int u[4]; bf16x8 v; } pa[4];
#pragma unroll
    for (int blk = 0; blk < 2; ++blk)
#pragma unroll
      for (int k1 = 0; k1 < 2; ++k1)
#pragma unroll
        for (int j = 0; j < 2; ++j) {
          unsigned int av = w[blk][2 * k1][j], bv = w[blk][2 * k1 + 1][j];
          asm volatile("v_permlane32_swap_b32 %0, %1" : "+v"(av), "+v"(bv));
          pa[blk * 2 + k1].u[j] = av;       // lo: own g=2k1 | hi: partner g=2k1+1
          pa[blk * 2 + k1].u[j + 2] = bv;   // lo: partner   | hi: own
        }

    // ---- PV: O[q][d] += P·V, 4 d-blocks x 4 k-steps
    __builtin_amdgcn_s_setprio(1);
#pragma unroll
    for (int dblk = 0; dblk < 4; ++dblk) {
      int drow = dblk * 32 + l31;
#pragma unroll
      for (int ks = 0; ks < 4; ++ks) {
        bf16x8 vf = *(const bf16x8*)&Vs[bsel][(drow * 8 + ((ks * 2 + hi) ^ (drow & 7))) * 8];
        o[dblk] = __builtin_amdgcn_mfma_f32_32x32x16_bf16(pa[ks].v, vf, o[dblk], 0, 0, 0);
      }
    }
    __builtin_amdgcn_s_setprio(0);
  }

  // ---- epilogue: normalize (row scale lives in lane q -> broadcast) + store
  float inv = 1.0f / lrow;
#pragma unroll
  for (int r = 0; r < 16; ++r) {
    int qloc = (r & 3) + 8 * (r >> 2) + 4 * hi;
    float ir = __shfl(inv, qloc, 64);
    int qrow = q0 + wave * 32 + qloc;
    size_t obase = ((size_t)(b * S_ + qrow)) * HID_ + h * HS_;
#pragma unroll
    for (int dblk = 0; dblk < 4; ++dblk)
      Out[obase + dblk * 32 + l31] = f2bf(o[dblk][r] * ir);
  }
}

// ---------------- launcher ----------------

extern "C" void kernel_launch(void* const* d_in, const int* in_sizes, int n_in,
                              void* d_out, int out_size, void* d_ws, size_t ws_size,
                              hipStream_t stream) {
  const float* hs    = (const float*)d_in[0];
  const float* amask = (const float*)d_in[1];
  const int*   pids  = (const int*)d_in[2];
  const float* Wqkv  = (const float*)d_in[3];
  const float* bqkv  = (const float*)d_in[4];
  const float* Wd    = (const float*)d_in[5];
  const float* bd    = (const float*)d_in[6];
  float* out = (float*)d_out;

  // workspace layout (96 MB):
  //  [0,16M)   Xb (bf16 X) -> reused as attn after gemm_qkv
  //  [16,40M)  WqkvT   [40,48M) WdT
  //  [48,64M)  Qb      [64,80M)  Kb      [80,96M)  Vt
  char* ws = (char*)d_ws;
  ushort_t* Xb    = (ushort_t*)(ws);
  ushort_t* WqkvT = (ushort_t*)(ws + ((size_t)16 << 20));
  ushort_t* WdT   = (ushort_t*)(ws + ((size_t)40 << 20));
  ushort_t* Qb    = (ushort_t*)(ws + ((size_t)48 << 20));
  ushort_t* Kb    = (ushort_t*)(ws + ((size_t)64 << 20));
  ushort_t* Vt    = (ushort_t*)(ws + ((size_t)80 << 20));
  ushort_t* attn  = Xb;

  prep<<<8192, 256, 0, stream>>>(hs, Wqkv, Wd, Xb, WqkvT, WdT);
  gemm_qkv<<<dim3(N_QKV / 128, (B_ * S_) / 128), 256, 0, stream>>>(
      Xb, WqkvT, bqkv, pids, Qb, Kb, Vt);
  flash_attn<<<dim3(S_ / 128, B_ * H_), 256, 0, stream>>>(Qb, Kb, Vt, amask, attn);
  gemm_bt<0><<<dim3(HID_ / 128, (B_ * S_) / 128), 256, 0, stream>>>(
      attn, WdT, bd, d_out, B_ * S_, HID_, HID_);
  (void)out; (void)in_sizes; (void)n_in; (void)out_size; (void)ws_size;
}